// Round 1
// baseline (434.462 us; speedup 1.0000x reference)
//
#include <hip/hip_runtime.h>
#include <hip/hip_bf16.h>

#define BB 64
#define SS 2048
#define HH 256

typedef __attribute__((ext_vector_type(8))) __bf16 bf16x8;
typedef __attribute__((ext_vector_type(4))) float f32x4;

__device__ __forceinline__ float tanh_fast(float x) {
  float e = __expf(2.0f * x);
  return __fdividef(e - 1.0f, e + 1.0f);
}

// k0: convert W (HxH fp32) -> bf16 in ws
__global__ __launch_bounds__(1024) void cvt_w_kernel(const float* __restrict__ w,
                                                     __bf16* __restrict__ wb) {
  int i = blockIdx.x * 1024 + threadIdx.x;
  wb[i] = (__bf16)w[i];
}

// k1: scores[r] = sum_k tanh(m_text[r,k])*Wc[k] + sum_k tanh(m_asp[r,k])*Wc[H+k]
// wave handles 16 rows; mfma 16x16x32 bf16; B^T layout (W stored [k_out][h]).
__global__ __launch_bounds__(256) void score_kernel(
    const float* __restrict__ text, const float* __restrict__ aspect,
    const __bf16* __restrict__ wbf, const float* __restrict__ wc,
    float* __restrict__ scores) {
  const int tid = threadIdx.x;
  const int lane = tid & 63;
  const int wid = tid >> 6;
  const int fr = lane & 15;   // A row within 16-row tile / B col (k_out) / D col
  const int fq = lane >> 4;   // 0..3: selects 8-elem K group / D row group
  const long rowBase = (long)blockIdx.x * 64 + (long)wid * 16;
  const float* trow = text + (rowBase + fr) * HH;
  const float* arow = aspect + (rowBase + fr) * HH;

  // Preload A fragments for both tensors: 8 chunks of K=32 (full H=256)
  bf16x8 at[8], aa[8];
#pragma unroll
  for (int c = 0; c < 8; ++c) {
    const f32x4* tp = (const f32x4*)(trow + c * 32 + fq * 8);
    const f32x4* ap = (const f32x4*)(arow + c * 32 + fq * 8);
    f32x4 t0 = tp[0], t1 = tp[1];
    f32x4 a0 = ap[0], a1 = ap[1];
    bf16x8 tt, av;
#pragma unroll
    for (int j = 0; j < 4; ++j) {
      tt[j] = (__bf16)t0[j]; tt[4 + j] = (__bf16)t1[j];
      av[j] = (__bf16)a0[j]; av[4 + j] = (__bf16)a1[j];
    }
    at[c] = tt; aa[c] = av;
  }

  float sp0 = 0.f, sp1 = 0.f, sp2 = 0.f, sp3 = 0.f;
#pragma unroll 1
  for (int nt = 0; nt < 16; ++nt) {
    f32x4 ct = {0.f, 0.f, 0.f, 0.f};
    f32x4 ca = {0.f, 0.f, 0.f, 0.f};
    const __bf16* wp = wbf + (nt * 16 + fr) * HH + fq * 8;
#pragma unroll
    for (int c = 0; c < 8; ++c) {
      bf16x8 bfr = *(const bf16x8*)(wp + c * 32);
      ct = __builtin_amdgcn_mfma_f32_16x16x32_bf16(at[c], bfr, ct, 0, 0, 0);
      ca = __builtin_amdgcn_mfma_f32_16x16x32_bf16(aa[c], bfr, ca, 0, 0, 0);
    }
    // lane holds m[row=rowBase+fq*4+j][k_out=nt*16+fr] in ct[j]/ca[j]
    float wct = wc[nt * 16 + fr];
    float wca = wc[HH + nt * 16 + fr];
    sp0 += tanh_fast(ct[0]) * wct + tanh_fast(ca[0]) * wca;
    sp1 += tanh_fast(ct[1]) * wct + tanh_fast(ca[1]) * wca;
    sp2 += tanh_fast(ct[2]) * wct + tanh_fast(ca[2]) * wca;
    sp3 += tanh_fast(ct[3]) * wct + tanh_fast(ca[3]) * wca;
  }
  // reduce over the 16 lanes (fr) of each fq group
#pragma unroll
  for (int off = 1; off < 16; off <<= 1) {
    sp0 += __shfl_xor(sp0, off, 64);
    sp1 += __shfl_xor(sp1, off, 64);
    sp2 += __shfl_xor(sp2, off, 64);
    sp3 += __shfl_xor(sp3, off, 64);
  }
  if (fr == 0) {
    long r = rowBase + fq * 4;
    scores[r + 0] = sp0;
    scores[r + 1] = sp1;
    scores[r + 2] = sp2;
    scores[r + 3] = sp3;
  }
}

// k2: per-batch softmax over S; writes weights to out[0:B*S]; zeroes out2 region
__global__ __launch_bounds__(256) void softmax_kernel(
    const float* __restrict__ scores, float* __restrict__ weight,
    float* __restrict__ out2) {
  const int b = blockIdx.x;
  const int tid = threadIdx.x;
  const int lane = tid & 63;
  const int wid = tid >> 6;
  const float* s = scores + (long)b * SS;
  float v[8];
  float mx = -1e30f;
#pragma unroll
  for (int i = 0; i < 8; ++i) {
    v[i] = s[tid + i * 256];
    mx = fmaxf(mx, v[i]);
  }
#pragma unroll
  for (int off = 32; off >= 1; off >>= 1) mx = fmaxf(mx, __shfl_xor(mx, off, 64));
  __shared__ float red[8];
  if (lane == 0) red[wid] = mx;
  __syncthreads();
  mx = fmaxf(fmaxf(red[0], red[1]), fmaxf(red[2], red[3]));
  float sum = 0.f;
#pragma unroll
  for (int i = 0; i < 8; ++i) {
    v[i] = __expf(v[i] - mx);
    sum += v[i];
  }
#pragma unroll
  for (int off = 32; off >= 1; off >>= 1) sum += __shfl_xor(sum, off, 64);
  if (lane == 0) red[4 + wid] = sum;
  __syncthreads();
  sum = red[4] + red[5] + red[6] + red[7];
  float inv = 1.0f / sum;
#pragma unroll
  for (int i = 0; i < 8; ++i) weight[(long)b * SS + tid + i * 256] = v[i] * inv;
  out2[b * HH + tid] = 0.0f;  // init for k3 atomics
}

// k3: out[b,h] = sum_s w[b,s]*text[b,s,h]; 8 S-chunks per batch, atomicAdd.
__global__ __launch_bounds__(256) void out_kernel(const float* __restrict__ text,
                                                  const float* __restrict__ weight,
                                                  float* __restrict__ out2) {
  const int b = blockIdx.x >> 3;
  const int ch = blockIdx.x & 7;
  const int tid = threadIdx.x;
  __shared__ float wsm[256];
  wsm[tid] = weight[(long)b * SS + ch * 256 + tid];
  __syncthreads();
  const float* t = text + ((long)b * SS + ch * 256) * HH;
  float acc = 0.f;
#pragma unroll 4
  for (int s = 0; s < 256; ++s) acc = fmaf(wsm[s], t[(long)s * HH + tid], acc);
  atomicAdd(&out2[b * HH + tid], acc);
}

extern "C" void kernel_launch(void* const* d_in, const int* in_sizes, int n_in,
                              void* d_out, int out_size, void* d_ws, size_t ws_size,
                              hipStream_t stream) {
  const float* text = (const float*)d_in[0];
  const float* aspect = (const float*)d_in[1];
  const float* w = (const float*)d_in[2];
  const float* wc = (const float*)d_in[3];

  float* weight = (float*)d_out;                 // [B*S] fp32
  float* out2 = weight + (long)BB * SS;          // [B*H] fp32

  float* scores = (float*)d_ws;                                    // 512 KB
  __bf16* wbf = (__bf16*)((char*)d_ws + (size_t)BB * SS * 4);      // 128 KB

  cvt_w_kernel<<<dim3(64), dim3(1024), 0, stream>>>(w, wbf);
  score_kernel<<<dim3(2048), dim3(256), 0, stream>>>(text, aspect, wbf, wc, scores);
  softmax_kernel<<<dim3(BB), dim3(256), 0, stream>>>(scores, weight, out2);
  out_kernel<<<dim3(BB * 8), dim3(256), 0, stream>>>(text, weight, out2);
}

// Round 2
// 344.995 us; speedup vs baseline: 1.2593x; 1.2593x over previous
//
#include <hip/hip_runtime.h>
#include <hip/hip_bf16.h>

#define BB 64
#define SS 2048
#define HH 256

typedef __attribute__((ext_vector_type(8))) __bf16 bf16x8;
typedef __attribute__((ext_vector_type(4))) float f32x4;

typedef __attribute__((address_space(1))) const unsigned int g_u32;
typedef __attribute__((address_space(3))) unsigned int l_u32;

__device__ __forceinline__ float tanh_fast(float x) {
  float e = __expf(2.0f * x);
  return __fdividef(e - 1.0f, e + 1.0f);
}

// k0: convert W (HxH fp32) -> bf16 in ws
__global__ __launch_bounds__(1024) void cvt_w_kernel(const float* __restrict__ w,
                                                     __bf16* __restrict__ wb) {
  int i = blockIdx.x * 1024 + threadIdx.x;
  wb[i] = (__bf16)w[i];
}

// k1: per block: 32 rows of text AND aspect staged to LDS (sigma-swizzled).
// Wave w owns k_out quarter [w*64, w*64+64) for all 4 sets
// (set = tensor*2 + rowhalf). Partials reduced via LDS into scores_t/scores_a.
__global__ __launch_bounds__(256, 2) void score_kernel(
    const float* __restrict__ text, const float* __restrict__ aspect,
    const __bf16* __restrict__ wbf, const float* __restrict__ wc,
    float* __restrict__ scores_t, float* __restrict__ scores_a) {
  __shared__ float smem[4 * 16 * 256 + 256];  // 64KB tiles + partial buffer
  float* partial = smem + 4 * 16 * 256;

  const int tid = threadIdx.x;
  const int lane = tid & 63;
  const int wid = tid >> 6;
  const int fr = lane & 15;  // MFMA A-row / B n-index / D col
  const int fq = lane >> 4;  // K-group / D row-group

  // ---- stage: wave wid stages set wid (16 rows x 1KB), swizzled source ----
  const float* tbase = (wid & 2) ? aspect : text;
  const long r0 = (long)blockIdx.x * 32 + ((wid & 1) << 4);
#pragma unroll
  for (int it = 0; it < 16; ++it) {
    const int sig = ((it & 7) << 3) | (it >> 3);
    const char* g = (const char*)(tbase + (r0 + it) * HH) + ((lane ^ sig) << 4);
    float* l = smem + wid * 4096 + it * 256;  // wave-uniform; HW adds lane*16B
    __builtin_amdgcn_global_load_lds((g_u32*)g, (l_u32*)l, 16, 0, 0);
  }
  __syncthreads();

  // ---- read A fragments for ALL 4 sets (swizzled, conflict-free) ----
  bf16x8 afr[4][8];
  const int sig_fr = ((fr & 7) << 3) | (fr >> 3);
#pragma unroll
  for (int set = 0; set < 4; ++set) {
    const char* base = (const char*)(smem + set * 4096 + fr * 256);
#pragma unroll
    for (int c = 0; c < 8; ++c) {
      const int u0 = c * 8 + fq * 2;  // 16B-slot of first half
      f32x4 v0 = *(const f32x4*)(base + ((u0 ^ sig_fr) << 4));
      f32x4 v1 = *(const f32x4*)(base + (((u0 + 1) ^ sig_fr) << 4));
      bf16x8 t;
#pragma unroll
      for (int j = 0; j < 4; ++j) {
        t[j] = (__bf16)v0[j];
        t[4 + j] = (__bf16)v1[j];
      }
      afr[set][c] = t;
    }
  }

  // ---- nt loop: this wave's 4 k_out tiles, B-frags shared across 4 sets ----
  float sp[4][4];
#pragma unroll
  for (int a = 0; a < 4; ++a)
#pragma unroll
    for (int j = 0; j < 4; ++j) sp[a][j] = 0.f;

#pragma unroll 1
  for (int i = 0; i < 4; ++i) {
    const int nt = wid * 4 + i;
    const __bf16* wp = wbf + (nt * 16 + fr) * HH + fq * 8;
    bf16x8 bfr[8];
#pragma unroll
    for (int c = 0; c < 8; ++c) bfr[c] = *(const bf16x8*)(wp + c * 32);
    const float wct = wc[nt * 16 + fr];
    const float wca = wc[HH + nt * 16 + fr];
#pragma unroll
    for (int set = 0; set < 4; ++set) {
      f32x4 cacc = {0.f, 0.f, 0.f, 0.f};
#pragma unroll
      for (int c = 0; c < 8; ++c)
        cacc = __builtin_amdgcn_mfma_f32_16x16x32_bf16(afr[set][c], bfr[c], cacc, 0, 0, 0);
      const float wcv = (set & 2) ? wca : wct;
#pragma unroll
      for (int j = 0; j < 4; ++j) sp[set][j] += tanh_fast(cacc[j]) * wcv;
    }
  }

  // ---- reduce over fr (16 lanes), stash per-wave partials ----
#pragma unroll
  for (int off = 1; off < 16; off <<= 1)
#pragma unroll
    for (int set = 0; set < 4; ++set)
#pragma unroll
      for (int j = 0; j < 4; ++j) sp[set][j] += __shfl_xor(sp[set][j], off, 64);
  if (fr == 0) {
#pragma unroll
    for (int set = 0; set < 4; ++set)
#pragma unroll
      for (int j = 0; j < 4; ++j)
        partial[wid * 64 + set * 16 + fq * 4 + j] = sp[set][j];
  }
  __syncthreads();
  if (tid < 64) {
    float s = partial[tid] + partial[64 + tid] + partial[128 + tid] + partial[192 + tid];
    float* dst = (tid & 32) ? scores_a : scores_t;
    dst[(long)blockIdx.x * 32 + (tid & 31)] = s;
  }
}

// k2: per-batch softmax over S; sums the split partial scores;
// writes weights to d_out[0:B*S]; zeroes the out region for k3 atomics.
__global__ __launch_bounds__(256) void softmax_kernel(
    const float* __restrict__ st, const float* __restrict__ sa,
    float* __restrict__ weight, float* __restrict__ out2) {
  const int b = blockIdx.x;
  const int tid = threadIdx.x;
  const int lane = tid & 63;
  const int wid = tid >> 6;
  float v[8];
  float mx = -1e30f;
#pragma unroll
  for (int i = 0; i < 8; ++i) {
    const long idx = (long)b * SS + tid + i * 256;
    v[i] = st[idx] + sa[idx];
    mx = fmaxf(mx, v[i]);
  }
#pragma unroll
  for (int off = 32; off >= 1; off >>= 1) mx = fmaxf(mx, __shfl_xor(mx, off, 64));
  __shared__ float red[8];
  if (lane == 0) red[wid] = mx;
  __syncthreads();
  mx = fmaxf(fmaxf(red[0], red[1]), fmaxf(red[2], red[3]));
  float sum = 0.f;
#pragma unroll
  for (int i = 0; i < 8; ++i) {
    v[i] = __expf(v[i] - mx);
    sum += v[i];
  }
#pragma unroll
  for (int off = 32; off >= 1; off >>= 1) sum += __shfl_xor(sum, off, 64);
  if (lane == 0) red[4 + wid] = sum;
  __syncthreads();
  sum = red[4] + red[5] + red[6] + red[7];
  const float inv = 1.0f / sum;
#pragma unroll
  for (int i = 0; i < 8; ++i) weight[(long)b * SS + tid + i * 256] = v[i] * inv;
  out2[b * HH + tid] = 0.0f;  // init for k3 atomics
}

// k3: out[b,h] = sum_s w[b,s]*text[b,s,h]; 32 chunks of 64 rows per batch.
__global__ __launch_bounds__(256) void out_kernel(const float* __restrict__ text,
                                                  const float* __restrict__ weight,
                                                  float* __restrict__ out2) {
  const int b = blockIdx.x >> 5;
  const int ch = blockIdx.x & 31;
  const int tid = threadIdx.x;
  __shared__ float wsm[64];
  if (tid < 64) wsm[tid] = weight[(long)b * SS + ch * 64 + tid];
  __syncthreads();
  const float* t = text + ((long)b * SS + ch * 64) * HH;
  float acc = 0.f;
#pragma unroll 8
  for (int s = 0; s < 64; ++s) acc = fmaf(wsm[s], t[(long)s * HH + tid], acc);
  atomicAdd(&out2[b * HH + tid], acc);
}

extern "C" void kernel_launch(void* const* d_in, const int* in_sizes, int n_in,
                              void* d_out, int out_size, void* d_ws, size_t ws_size,
                              hipStream_t stream) {
  const float* text = (const float*)d_in[0];
  const float* aspect = (const float*)d_in[1];
  const float* w = (const float*)d_in[2];
  const float* wc = (const float*)d_in[3];

  float* weight = (float*)d_out;         // [B*S] fp32
  float* out2 = weight + (long)BB * SS;  // [B*H] fp32

  float* scores_t = (float*)d_ws;                                   // 512 KB
  float* scores_a = scores_t + (long)BB * SS;                       // 512 KB
  __bf16* wbf = (__bf16*)(scores_a + (long)BB * SS);                // 128 KB

  cvt_w_kernel<<<dim3(64), dim3(1024), 0, stream>>>(w, wbf);
  score_kernel<<<dim3(4096), dim3(256), 0, stream>>>(text, aspect, wbf, wc,
                                                     scores_t, scores_a);
  softmax_kernel<<<dim3(BB), dim3(256), 0, stream>>>(scores_t, scores_a, weight, out2);
  out_kernel<<<dim3(BB * 32), dim3(256), 0, stream>>>(text, weight, out2);
}

// Round 3
// 317.805 us; speedup vs baseline: 1.3671x; 1.0856x over previous
//
#include <hip/hip_runtime.h>
#include <hip/hip_bf16.h>

#define BB 64
#define SS 2048
#define HH 256
#define NTILES 16  // tiles per block
#define TROWS 32   // rows per tile per tensor

typedef __attribute__((ext_vector_type(8))) __bf16 bf16x8;
typedef __attribute__((ext_vector_type(4))) float f32x4;

__device__ __forceinline__ float tanh_fast(float x) {
  float e = __expf(2.0f * x);
  return __fdividef(e - 1.0f, e + 1.0f);
}

__device__ __forceinline__ bf16x8 pack8(f32x4 a, f32x4 b) {
  bf16x8 r;
  r[0] = (__bf16)a[0]; r[1] = (__bf16)a[1]; r[2] = (__bf16)a[2]; r[3] = (__bf16)a[3];
  r[4] = (__bf16)b[0]; r[5] = (__bf16)b[1]; r[6] = (__bf16)b[2]; r[7] = (__bf16)b[3];
  return r;
}

// k0: convert W (HxH fp32) -> bf16 in ws
__global__ __launch_bounds__(1024) void cvt_w_kernel(const float* __restrict__ w,
                                                     __bf16* __restrict__ wb) {
  int i = blockIdx.x * 1024 + threadIdx.x;
  wb[i] = (__bf16)w[i];
}

// k1: persistent 512-thread blocks; 16 tiles of 32 rows (text+aspect).
// Reg-staged f32->bf16->LDS (swizzled u^=(row&7)); W frags + wc persistent in
// registers; swapped mfma(W, text) puts k_out on D-rows so the score reduce is
// 4 lane-local adds + 2 shfl_xor. Single barrier per tile.
__global__ __launch_bounds__(512, 2) void score_kernel(
    const float* __restrict__ text, const float* __restrict__ aspect,
    const __bf16* __restrict__ wbf, const float* __restrict__ wc,
    float* __restrict__ scores_t, float* __restrict__ scores_a) {
  __shared__ __bf16 sbuf[2][64][256];   // 64 KB: [buf][cr=set*32+row][h]
  __shared__ float pr[2][8][2][2][16];  // 8 KB: [par][wave][set][half][fr]

  const int tid = threadIdx.x;
  const int lane = tid & 63;
  const int wid = tid >> 6;
  const int fr = lane & 15;
  const int fq = lane >> 4;
  const long blockRow0 = (long)blockIdx.x * (NTILES * TROWS);

  // ---- persistent W fragments (wave owns k_out [wid*32, wid*32+32)) + wc ----
  bf16x8 wf[2][8];
  float wcv[2][2][4];
#pragma unroll
  for (int nti = 0; nti < 2; ++nti) {
    const int nt = wid * 2 + nti;
    const __bf16* wp = wbf + (nt * 16 + fr) * HH + fq * 8;
#pragma unroll
    for (int c = 0; c < 8; ++c) wf[nti][c] = *(const bf16x8*)(wp + c * 32);
#pragma unroll
    for (int r = 0; r < 4; ++r) {
      wcv[0][nti][r] = wc[nt * 16 + fq * 4 + r];
      wcv[1][nti][r] = wc[HH + nt * 16 + fq * 4 + r];
    }
  }

  f32x4 reg[8];

  auto issue_loads = [&](int t) {
    const long R = blockRow0 + (long)t * TROWS;
#pragma unroll
    for (int rr = 0; rr < 4; ++rr) {
      const int cr = wid * 8 + rr * 2 + (lane >> 5);
      const float* base = (cr & 32) ? aspect : text;
      const float* p = base + (R + (cr & 31)) * HH + (lane & 31) * 8;
      reg[rr * 2] = *(const f32x4*)p;
      reg[rr * 2 + 1] = *(const f32x4*)(p + 4);
    }
  };
  auto write_stage = [&](int pb) {
#pragma unroll
    for (int rr = 0; rr < 4; ++rr) {
      const int cr = wid * 8 + rr * 2 + (lane >> 5);
      const int up = (lane & 31) ^ (cr & 7);
      *(bf16x8*)&sbuf[pb][cr][up * 8] = pack8(reg[rr * 2], reg[rr * 2 + 1]);
    }
  };
  auto compute = [&](int pb, int par) {
#pragma unroll
    for (int set = 0; set < 2; ++set)
#pragma unroll
      for (int half = 0; half < 2; ++half) {
        const int cr = set * 32 + half * 16 + fr;
        const __bf16* rowp = &sbuf[pb][cr][0];
        bf16x8 tf[8];
#pragma unroll
        for (int c = 0; c < 8; ++c) {
          const int u = c * 4 + fq;
          tf[c] = *(const bf16x8*)(rowp + (u ^ (fr & 7)) * 8);
        }
        f32x4 a0 = {0.f, 0.f, 0.f, 0.f}, a1 = {0.f, 0.f, 0.f, 0.f};
#pragma unroll
        for (int c = 0; c < 8; ++c) {
          a0 = __builtin_amdgcn_mfma_f32_16x16x32_bf16(wf[0][c], tf[c], a0, 0, 0, 0);
          a1 = __builtin_amdgcn_mfma_f32_16x16x32_bf16(wf[1][c], tf[c], a1, 0, 0, 0);
        }
        float p = 0.f;
#pragma unroll
        for (int r = 0; r < 4; ++r)
          p += tanh_fast(a0[r]) * wcv[set][0][r] + tanh_fast(a1[r]) * wcv[set][1][r];
        p += __shfl_xor(p, 16, 64);
        p += __shfl_xor(p, 32, 64);
        if (fq == 0) pr[par][wid][set][half][fr] = p;
      }
  };
  auto reduce_out = [&](int t) {
    if (tid < 64) {
      const int par = t & 1;
      const int set = tid >> 5;
      const int r = tid & 31;
      float s = 0.f;
#pragma unroll
      for (int w = 0; w < 8; ++w) s += pr[par][w][set][r >> 4][r & 15];
      (set ? scores_a : scores_t)[blockRow0 + (long)t * TROWS + r] = s;
    }
  };

  // ---- prologue: stage tile 0 ----
  issue_loads(0);
  write_stage(0);
  __syncthreads();

#pragma unroll 1
  for (int t = 0; t < NTILES; ++t) {
    const int pb = t & 1;
    if (t + 1 < NTILES) issue_loads(t + 1);
    if (t > 0) reduce_out(t - 1);
    compute(pb, t & 1);
    if (t + 1 < NTILES) write_stage(pb ^ 1);
    __syncthreads();
  }
  reduce_out(NTILES - 1);
}

// k2: per-batch softmax over S; sums split partials; writes weight; zeroes out2
__global__ __launch_bounds__(256) void softmax_kernel(
    const float* __restrict__ st, const float* __restrict__ sa,
    float* __restrict__ weight, float* __restrict__ out2) {
  const int b = blockIdx.x;
  const int tid = threadIdx.x;
  const int lane = tid & 63;
  const int wid = tid >> 6;
  float v[8];
  float mx = -1e30f;
#pragma unroll
  for (int i = 0; i < 8; ++i) {
    const long idx = (long)b * SS + tid + i * 256;
    v[i] = st[idx] + sa[idx];
    mx = fmaxf(mx, v[i]);
  }
#pragma unroll
  for (int off = 32; off >= 1; off >>= 1) mx = fmaxf(mx, __shfl_xor(mx, off, 64));
  __shared__ float red[8];
  if (lane == 0) red[wid] = mx;
  __syncthreads();
  mx = fmaxf(fmaxf(red[0], red[1]), fmaxf(red[2], red[3]));
  float sum = 0.f;
#pragma unroll
  for (int i = 0; i < 8; ++i) {
    v[i] = __expf(v[i] - mx);
    sum += v[i];
  }
#pragma unroll
  for (int off = 32; off >= 1; off >>= 1) sum += __shfl_xor(sum, off, 64);
  if (lane == 0) red[4 + wid] = sum;
  __syncthreads();
  sum = red[4] + red[5] + red[6] + red[7];
  const float inv = 1.0f / sum;
#pragma unroll
  for (int i = 0; i < 8; ++i) weight[(long)b * SS + tid + i * 256] = v[i] * inv;
  out2[b * HH + tid] = 0.0f;  // init for k3 atomics
}

// k3: out[b,h] = sum_s w[b,s]*text[b,s,h]; 32 chunks of 64 rows per batch.
__global__ __launch_bounds__(256) void out_kernel(const float* __restrict__ text,
                                                  const float* __restrict__ weight,
                                                  float* __restrict__ out2) {
  const int b = blockIdx.x >> 5;
  const int ch = blockIdx.x & 31;
  const int tid = threadIdx.x;
  __shared__ float wsm[64];
  if (tid < 64) wsm[tid] = weight[(long)b * SS + ch * 64 + tid];
  __syncthreads();
  const float* t = text + ((long)b * SS + ch * 64) * HH;
  float acc = 0.f;
#pragma unroll 8
  for (int s = 0; s < 64; ++s) acc = fmaf(wsm[s], t[(long)s * HH + tid], acc);
  atomicAdd(&out2[b * HH + tid], acc);
}

extern "C" void kernel_launch(void* const* d_in, const int* in_sizes, int n_in,
                              void* d_out, int out_size, void* d_ws, size_t ws_size,
                              hipStream_t stream) {
  const float* text = (const float*)d_in[0];
  const float* aspect = (const float*)d_in[1];
  const float* w = (const float*)d_in[2];
  const float* wc = (const float*)d_in[3];

  float* weight = (float*)d_out;         // [B*S] fp32
  float* out2 = weight + (long)BB * SS;  // [B*H] fp32

  float* scores_t = (float*)d_ws;                     // 512 KB
  float* scores_a = scores_t + (long)BB * SS;         // 512 KB
  __bf16* wbf = (__bf16*)(scores_a + (long)BB * SS);  // 128 KB

  cvt_w_kernel<<<dim3(64), dim3(1024), 0, stream>>>(w, wbf);
  score_kernel<<<dim3(256), dim3(512), 0, stream>>>(text, aspect, wbf, wc,
                                                    scores_t, scores_a);
  softmax_kernel<<<dim3(BB), dim3(256), 0, stream>>>(scores_t, scores_a, weight, out2);
  out_kernel<<<dim3(BB * 32), dim3(256), 0, stream>>>(text, weight, out2);
}